// Round 1
// baseline (1806.475 us; speedup 1.0000x reference)
//
#include <hip/hip_runtime.h>
#include <hip/hip_bf16.h>

#define N_TOK   2048
#define DM      1024   // d_model
#define DF      4096   // d_ff
#define NE      8
#define TOPK    2

#define TM 64
#define TN 64
#define KB 16

// ---------------- init ----------------
__global__ void k_init(int* counts, float* probs_sum) {
    int i = threadIdx.x;
    if (i < NE) { counts[i] = 0; probs_sum[i] = 0.f; }
}

// ---------------- router: 1 wave per token ----------------
__global__ __launch_bounds__(64) void k_router(
    const float* __restrict__ x, const float* __restrict__ rw,
    int* counts, float* probs_sum,
    int* pair_exp, int* pair_pos, float* topp, int* pair_token)
{
    int t = blockIdx.x;
    int lane = threadIdx.x;
    const float* xt = x + (size_t)t * DM;

    float acc[NE];
#pragma unroll
    for (int e = 0; e < NE; e++) acc[e] = 0.f;

    for (int i = lane; i < DM; i += 64) {
        float xv = xt[i];
#pragma unroll
        for (int e = 0; e < NE; e++)
            acc[e] = fmaf(xv, rw[e * DM + i], acc[e]);
    }
#pragma unroll
    for (int off = 32; off > 0; off >>= 1) {
#pragma unroll
        for (int e = 0; e < NE; e++)
            acc[e] += __shfl_down(acc[e], off);
    }

    if (lane == 0) {
        // full softmax for aux loss
        float m = acc[0];
#pragma unroll
        for (int e = 1; e < NE; e++) m = fmaxf(m, acc[e]);
        float p[NE]; float s = 0.f;
#pragma unroll
        for (int e = 0; e < NE; e++) { p[e] = expf(acc[e] - m); s += p[e]; }
        float inv = 1.f / s;
#pragma unroll
        for (int e = 0; e < NE; e++) atomicAdd(&probs_sum[e], p[e] * inv);

        // top-2, ties -> lower index (strict >)
        int i0 = 0;
#pragma unroll
        for (int e = 1; e < NE; e++) if (acc[e] > acc[i0]) i0 = e;
        int i1 = (i0 == 0) ? 1 : 0;
#pragma unroll
        for (int e = 0; e < NE; e++) if (e != i0 && acc[e] > acc[i1]) i1 = e;

        float v0 = acc[i0], v1 = acc[i1];
        float e1 = expf(v1 - v0);
        float denom = 1.f / (1.f + e1);
        float p0 = denom;
        float p1 = e1 * denom;

        topp[t * 2 + 0] = p0;
        topp[t * 2 + 1] = p1;
        pair_exp[t * 2 + 0] = i0;
        pair_exp[t * 2 + 1] = i1;

        int pos0 = atomicAdd(&counts[i0], 1);
        pair_token[i0 * N_TOK + pos0] = t;
        pair_pos[t * 2 + 0] = pos0;
        int pos1 = atomicAdd(&counts[i1], 1);
        pair_token[i1 * N_TOK + pos1] = t;
        pair_pos[t * 2 + 1] = pos1;
    }
}

// ---------------- offsets + aux loss ----------------
__global__ void k_offsets(const int* counts, const float* probs_sum,
                          int* expert_offset, float* out_aux)
{
    if (threadIdx.x == 0 && blockIdx.x == 0) {
        int off = 0;
        for (int e = 0; e < NE; e++) { expert_offset[e] = off; off += counts[e]; }
        expert_offset[NE] = off;
        float aux = 0.f;
        for (int e = 0; e < NE; e++) {
            float ep = probs_sum[e] / (float)N_TOK;
            aux += ep * ep;
        }
        out_aux[0] = 0.01f * (float)NE * aux;
    }
}

// ---------------- pass A: H = silu(X W1) * (X W3), grouped by expert ----------------
__global__ __launch_bounds__(256) void k_ffn1(
    const float* __restrict__ x,
    const float* __restrict__ w1, const float* __restrict__ w3,
    const int* __restrict__ counts, const int* __restrict__ expert_offset,
    const int* __restrict__ pair_token, __hip_bfloat16* __restrict__ H)
{
    int e = blockIdx.z;
    int cnt = counts[e];
    int m0 = blockIdx.y * TM;
    if (m0 >= cnt) return;
    int f0 = blockIdx.x * TN;
    int row_base = expert_offset[e];

    __shared__ float xs[TM][20];          // KB=16 cols, pad to 20 (16B-aligned rows)
    __shared__ float w1s[KB][TN];
    __shared__ float w3s[KB][TN];

    int tid = threadIdx.x;
    int tx = tid & 15, ty = tid >> 4;
    int ty4 = ty * 4, tx4 = tx * 4;

    // staging roles
    int sr  = tid >> 2;            // 0..63 : row of x tile
    int sk4 = (tid & 3) * 4;       // 0,4,8,12
    int wk  = tid >> 4;            // 0..15 : k-row of w tile
    int wn4 = (tid & 15) * 4;      // 0..60

    int tok = pair_token[e * N_TOK + min(m0 + sr, cnt - 1)];
    const float* xrow = x + (size_t)tok * DM;
    const float* w1p = w1 + (size_t)e * DM * DF + f0;
    const float* w3p = w3 + (size_t)e * DM * DF + f0;

    float g[4][4], u[4][4];
#pragma unroll
    for (int i = 0; i < 4; i++)
#pragma unroll
        for (int j = 0; j < 4; j++) { g[i][j] = 0.f; u[i][j] = 0.f; }

    for (int c0 = 0; c0 < DM; c0 += KB) {
        float4 xv  = *(const float4*)(xrow + c0 + sk4);
        float4 w1v = *(const float4*)(w1p + (size_t)(c0 + wk) * DF + wn4);
        float4 w3v = *(const float4*)(w3p + (size_t)(c0 + wk) * DF + wn4);
        *(float4*)&xs[sr][sk4]  = xv;
        *(float4*)&w1s[wk][wn4] = w1v;
        *(float4*)&w3s[wk][wn4] = w3v;
        __syncthreads();
#pragma unroll
        for (int kk = 0; kk < KB; kk++) {
            float a0 = xs[ty4 + 0][kk];
            float a1 = xs[ty4 + 1][kk];
            float a2 = xs[ty4 + 2][kk];
            float a3 = xs[ty4 + 3][kk];
            float4 b1 = *(const float4*)&w1s[kk][tx4];
            float4 b3 = *(const float4*)&w3s[kk][tx4];
            float b1a[4] = {b1.x, b1.y, b1.z, b1.w};
            float b3a[4] = {b3.x, b3.y, b3.z, b3.w};
            float aa[4] = {a0, a1, a2, a3};
#pragma unroll
            for (int i = 0; i < 4; i++) {
#pragma unroll
                for (int j = 0; j < 4; j++) {
                    g[i][j] = fmaf(aa[i], b1a[j], g[i][j]);
                    u[i][j] = fmaf(aa[i], b3a[j], u[i][j]);
                }
            }
        }
        __syncthreads();
    }

    // epilogue: h = silu(g)*u -> bf16
#pragma unroll
    for (int i = 0; i < 4; i++) {
        int m = m0 + ty4 + i;
        if (m < cnt) {
            size_t rg = (size_t)(row_base + m);
            ushort4 pk;
            unsigned short* pr = &pk.x;
#pragma unroll
            for (int j = 0; j < 4; j++) {
                float gv = g[i][j];
                float hv = (gv / (1.f + expf(-gv))) * u[i][j];
                __hip_bfloat16 hb = __float2bfloat16(hv);
                pr[j] = *reinterpret_cast<unsigned short*>(&hb);
            }
            *(ushort4*)&H[rg * DF + f0 + tx4] = pk;
        }
    }
}

// ---------------- pass B: Y = H W2, grouped by expert ----------------
__global__ __launch_bounds__(256) void k_ffn2(
    const __hip_bfloat16* __restrict__ H, const float* __restrict__ w2,
    const int* __restrict__ counts, const int* __restrict__ expert_offset,
    float* __restrict__ Y)
{
    int e = blockIdx.z;
    int cnt = counts[e];
    int m0 = blockIdx.y * TM;
    if (m0 >= cnt) return;
    int c0 = blockIdx.x * TN;
    int row_base = expert_offset[e];

    __shared__ float hs[TM][20];
    __shared__ float w2s[KB][TN];

    int tid = threadIdx.x;
    int tx = tid & 15, ty = tid >> 4;
    int ty4 = ty * 4, tx4 = tx * 4;

    int sr  = tid >> 2;
    int sk4 = (tid & 3) * 4;
    int wk  = tid >> 4;
    int wn4 = (tid & 15) * 4;

    size_t hrow = (size_t)(row_base + min(m0 + sr, cnt - 1)) * DF;
    const float* w2p = w2 + (size_t)e * DF * DM + c0;

    float y[4][4];
#pragma unroll
    for (int i = 0; i < 4; i++)
#pragma unroll
        for (int j = 0; j < 4; j++) y[i][j] = 0.f;

    for (int f0 = 0; f0 < DF; f0 += KB) {
        ushort4 hv = *(const ushort4*)&H[hrow + f0 + sk4];
        float4 w2v = *(const float4*)(w2p + (size_t)(f0 + wk) * DM + wn4);
        hs[sr][sk4 + 0] = __uint_as_float((unsigned)hv.x << 16);
        hs[sr][sk4 + 1] = __uint_as_float((unsigned)hv.y << 16);
        hs[sr][sk4 + 2] = __uint_as_float((unsigned)hv.z << 16);
        hs[sr][sk4 + 3] = __uint_as_float((unsigned)hv.w << 16);
        *(float4*)&w2s[wk][wn4] = w2v;
        __syncthreads();
#pragma unroll
        for (int kk = 0; kk < KB; kk++) {
            float aa[4] = {hs[ty4 + 0][kk], hs[ty4 + 1][kk],
                           hs[ty4 + 2][kk], hs[ty4 + 3][kk]};
            float4 b2 = *(const float4*)&w2s[kk][tx4];
            float ba[4] = {b2.x, b2.y, b2.z, b2.w};
#pragma unroll
            for (int i = 0; i < 4; i++)
#pragma unroll
                for (int j = 0; j < 4; j++)
                    y[i][j] = fmaf(aa[i], ba[j], y[i][j]);
        }
        __syncthreads();
    }

#pragma unroll
    for (int i = 0; i < 4; i++) {
        int m = m0 + ty4 + i;
        if (m < cnt) {
            size_t rg = (size_t)(row_base + m);
            float4 o = make_float4(y[i][0], y[i][1], y[i][2], y[i][3]);
            *(float4*)&Y[rg * DM + c0 + tx4] = o;
        }
    }
}

// ---------------- combine: out[t] = p0*Y[r0] + p1*Y[r1] ----------------
__global__ __launch_bounds__(256) void k_combine(
    const float* __restrict__ Y,
    const int* __restrict__ pair_exp, const int* __restrict__ pair_pos,
    const float* __restrict__ topp, const int* __restrict__ expert_offset,
    float* __restrict__ out)
{
    int t = blockIdx.x;
    int c4 = threadIdx.x * 4;
    int e0 = pair_exp[t * 2], e1 = pair_exp[t * 2 + 1];
    size_t r0 = (size_t)(expert_offset[e0] + pair_pos[t * 2]);
    size_t r1 = (size_t)(expert_offset[e1] + pair_pos[t * 2 + 1]);
    float p0 = topp[t * 2], p1 = topp[t * 2 + 1];
    float4 a = *(const float4*)&Y[r0 * DM + c4];
    float4 b = *(const float4*)&Y[r1 * DM + c4];
    float4 o;
    o.x = p0 * a.x + p1 * b.x;
    o.y = p0 * a.y + p1 * b.y;
    o.z = p0 * a.z + p1 * b.z;
    o.w = p0 * a.w + p1 * b.w;
    *(float4*)&out[(size_t)t * DM + c4] = o;
}

extern "C" void kernel_launch(void* const* d_in, const int* in_sizes, int n_in,
                              void* d_out, int out_size, void* d_ws, size_t ws_size,
                              hipStream_t stream)
{
    const float* x  = (const float*)d_in[0];
    const float* rw = (const float*)d_in[1];
    const float* w1 = (const float*)d_in[2];
    const float* w3 = (const float*)d_in[3];
    const float* w2 = (const float*)d_in[4];
    float* out = (float*)d_out;

    char* ws = (char*)d_ws;
    int*   counts        = (int*)(ws + 0);
    float* probs_sum     = (float*)(ws + 32);
    int*   expert_offset = (int*)(ws + 64);
    int*   pair_exp      = (int*)(ws + 128);
    int*   pair_pos      = (int*)(ws + 128 + 16384);
    float* topp          = (float*)(ws + 128 + 32768);
    int*   pair_token    = (int*)(ws + 128 + 49152);
    __hip_bfloat16* H    = (__hip_bfloat16*)(ws + (1 << 17));
    float* Y             = (float*)(ws + (1 << 17) + (size_t)N_TOK * TOPK * DF * 2);

    k_init<<<1, 64, 0, stream>>>(counts, probs_sum);
    k_router<<<N_TOK, 64, 0, stream>>>(x, rw, counts, probs_sum,
                                       pair_exp, pair_pos, topp, pair_token);
    k_offsets<<<1, 64, 0, stream>>>(counts, probs_sum, expert_offset,
                                    out + (size_t)N_TOK * DM);
    k_ffn1<<<dim3(DF / TN, N_TOK / TM, NE), 256, 0, stream>>>(
        x, w1, w3, counts, expert_offset, pair_token, H);
    k_ffn2<<<dim3(DM / TN, N_TOK / TM, NE), 256, 0, stream>>>(
        H, w2, counts, expert_offset, Y);
    k_combine<<<N_TOK, 256, 0, stream>>>(Y, pair_exp, pair_pos, topp,
                                         expert_offset, out);
}

// Round 2
// 610.960 us; speedup vs baseline: 2.9568x; 2.9568x over previous
//
#include <hip/hip_runtime.h>
#include <hip/hip_bf16.h>
#include <hip/hip_fp16.h>

#define NTOK 2048
#define DM   1024
#define DF   4096
#define NE   8
#define NROWS (NTOK * 2)

typedef _Float16 f16x8 __attribute__((ext_vector_type(8)));
typedef float    f32x4 __attribute__((ext_vector_type(4)));

__device__ __forceinline__ void gload_lds16(const void* g, void* l) {
    __builtin_amdgcn_global_load_lds(
        (const __attribute__((address_space(1))) void*)g,
        (__attribute__((address_space(3))) void*)l, 16, 0, 0);
}

// ---------------- init ----------------
__global__ void k_init(int* counts, float* probs_sum) {
    int i = threadIdx.x;
    if (i < NE) { counts[i] = 0; probs_sum[i] = 0.f; }
}

// ---------------- router: 1 wave per token ----------------
__global__ __launch_bounds__(64) void k_router(
    const float* __restrict__ x, const float* __restrict__ rw,
    int* counts, float* probs_sum,
    int* pair_exp, int* pair_pos, float* topp)
{
    int t = blockIdx.x;
    int lane = threadIdx.x;
    const float* xt = x + (size_t)t * DM;

    float acc[NE];
#pragma unroll
    for (int e = 0; e < NE; e++) acc[e] = 0.f;

    for (int i = lane; i < DM; i += 64) {
        float xv = xt[i];
#pragma unroll
        for (int e = 0; e < NE; e++)
            acc[e] = fmaf(xv, rw[e * DM + i], acc[e]);
    }
#pragma unroll
    for (int off = 32; off > 0; off >>= 1) {
#pragma unroll
        for (int e = 0; e < NE; e++)
            acc[e] += __shfl_down(acc[e], off);
    }

    if (lane == 0) {
        float m = acc[0];
#pragma unroll
        for (int e = 1; e < NE; e++) m = fmaxf(m, acc[e]);
        float p[NE]; float s = 0.f;
#pragma unroll
        for (int e = 0; e < NE; e++) { p[e] = expf(acc[e] - m); s += p[e]; }
        float inv = 1.f / s;
#pragma unroll
        for (int e = 0; e < NE; e++) atomicAdd(&probs_sum[e], p[e] * inv);

        int i0 = 0;
#pragma unroll
        for (int e = 1; e < NE; e++) if (acc[e] > acc[i0]) i0 = e;
        int i1 = (i0 == 0) ? 1 : 0;
#pragma unroll
        for (int e = 0; e < NE; e++) if (e != i0 && acc[e] > acc[i1]) i1 = e;

        float e1 = expf(acc[i1] - acc[i0]);
        float den = 1.f / (1.f + e1);
        topp[t * 2 + 0] = den;
        topp[t * 2 + 1] = e1 * den;
        pair_exp[t * 2 + 0] = i0;
        pair_exp[t * 2 + 1] = i1;
        pair_pos[t * 2 + 0] = atomicAdd(&counts[i0], 1);
        pair_pos[t * 2 + 1] = atomicAdd(&counts[i1], 1);
    }
}

// ---------------- offsets + aux loss ----------------
__global__ void k_offsets(const int* counts, const float* probs_sum,
                          int* eoff, float* out_aux)
{
    if (threadIdx.x == 0 && blockIdx.x == 0) {
        int off = 0;
        for (int e = 0; e < NE; e++) { eoff[e] = off; off += counts[e]; }
        eoff[NE] = off;
        float aux = 0.f;
        for (int e = 0; e < NE; e++) {
            float ep = probs_sum[e] / (float)NTOK;
            aux += ep * ep;
        }
        out_aux[0] = 0.01f * (float)NE * aux;
    }
}

// ---------------- gather tokens into grouped rows (fp32 -> fp16) ----------------
__global__ __launch_bounds__(256) void k_gather(
    const float* __restrict__ x, const int* __restrict__ pair_exp,
    const int* __restrict__ pair_pos, const int* __restrict__ eoff,
    _Float16* __restrict__ Xg)
{
    int b = blockIdx.x;
    int t = b >> 1, s = b & 1;
    int e = pair_exp[t * 2 + s];
    int row = eoff[e] + pair_pos[t * 2 + s];
    int c = threadIdx.x << 2;
    float4 v = *(const float4*)(x + (size_t)t * DM + c);
    _Float16 h0 = (_Float16)v.x, h1 = (_Float16)v.y,
             h2 = (_Float16)v.z, h3 = (_Float16)v.w;
    ushort4 o = make_ushort4(*(unsigned short*)&h0, *(unsigned short*)&h1,
                             *(unsigned short*)&h2, *(unsigned short*)&h3);
    *(ushort4*)(Xg + (size_t)row * DM + c) = o;
}

// ---------------- transpose + convert: W[e][K][N] fp32 -> Wt[e][N][K] fp16 ----------------
__global__ __launch_bounds__(256) void k_transpose(
    const float* __restrict__ W, _Float16* __restrict__ Wt, int K, int N)
{
    int e = blockIdx.z;
    int n0 = blockIdx.x << 6, k0 = blockIdx.y << 6;
    const float* src = W + (size_t)e * K * N;
    _Float16* dst = Wt + (size_t)e * N * K;
    __shared__ float tile[64][65];
    int tid = threadIdx.x;
    int tk = tid >> 4, tn = (tid & 15) << 2;
#pragma unroll
    for (int r = 0; r < 4; r++) {
        float4 v = *(const float4*)(src + (size_t)(k0 + tk + (r << 4)) * N + n0 + tn);
        float* trow = &tile[tk + (r << 4)][tn];
        trow[0] = v.x; trow[1] = v.y; trow[2] = v.z; trow[3] = v.w;
    }
    __syncthreads();
    int on = tid >> 2, ok = (tid & 3) << 4;
    unsigned pk[8];
#pragma unroll
    for (int p2 = 0; p2 < 8; p2++) {
        _Float16 a = (_Float16)tile[ok + 2 * p2][on];
        _Float16 b = (_Float16)tile[ok + 2 * p2 + 1][on];
        pk[p2] = (unsigned)(*(unsigned short*)&a) | ((unsigned)(*(unsigned short*)&b) << 16);
    }
    _Float16* d = dst + (size_t)(n0 + on) * K + k0 + ok;
    *(uint4*)d       = make_uint4(pk[0], pk[1], pk[2], pk[3]);
    *(uint4*)(d + 8) = make_uint4(pk[4], pk[5], pk[6], pk[7]);
}

// ---------------- grouped GEMM: C[m][n] = sum_k A[m][k] * Bt[n][k] ----------------
// EPI: 0 = store fp16 (gate G), 1 = read G, store fp16 silu(G)*acc (H), 2 = store fp32 (Y)
template<int EPI>
__global__ __launch_bounds__(256, 3) void k_gemm(
    const _Float16* __restrict__ A, const _Float16* __restrict__ Bt,
    const _Float16* __restrict__ Gin, void* __restrict__ Out,
    const int* __restrict__ counts, const int* __restrict__ eoff,
    int K, int N)
{
    int e = blockIdx.z;
    int cnt = counts[e];
    int m0 = blockIdx.y << 7;
    if (m0 >= cnt) return;
    int n0 = blockIdx.x << 7;
    int rb = eoff[e];

    __shared__ __align__(16) unsigned char sA[16384];   // [128][64] f16, slot-swizzled
    __shared__ __align__(16) unsigned char sB[16384];

    int tid = threadIdx.x;
    int lane = tid & 63;
    int w = tid >> 6;
    int wr = (w >> 1) << 6, wc = (w & 1) << 6;
    int l15 = lane & 15, l4 = lane >> 4;

    const _Float16* Ab = A + (size_t)(rb + m0) * K;
    const _Float16* Bb = Bt + ((size_t)e * N + n0) * K;

    f32x4 acc[4][4];
#pragma unroll
    for (int i = 0; i < 4; i++)
#pragma unroll
        for (int j = 0; j < 4; j++) acc[i][j] = (f32x4){0.f, 0.f, 0.f, 0.f};

    for (int k0 = 0; k0 < K; k0 += 64) {
        // stage: linear LDS dest, inverse-swizzled global source (16B chunks)
#pragma unroll
        for (int i = 0; i < 4; i++) {
            int c = (i << 8) + tid;
            int row = c >> 3;
            int sl = (c & 7) ^ (row & 7);
            size_t go = (size_t)row * K + k0 + (sl << 3);
            gload_lds16(Ab + go, sA + (c << 4));
            gload_lds16(Bb + go, sB + (c << 4));
        }
        __syncthreads();
#pragma unroll
        for (int kk = 0; kk < 2; kk++) {
            f16x8 af[4], bfr[4];
#pragma unroll
            for (int i = 0; i < 4; i++) {
                int r = wr + (i << 4) + l15;
                af[i] = *(const f16x8*)(sA + (r << 7) + ((((kk << 2) + l4) ^ (r & 7)) << 4));
            }
#pragma unroll
            for (int j = 0; j < 4; j++) {
                int r = wc + (j << 4) + l15;
                bfr[j] = *(const f16x8*)(sB + (r << 7) + ((((kk << 2) + l4) ^ (r & 7)) << 4));
            }
#pragma unroll
            for (int i = 0; i < 4; i++)
#pragma unroll
                for (int j = 0; j < 4; j++)
                    acc[i][j] = __builtin_amdgcn_mfma_f32_16x16x32_f16(af[i], bfr[j], acc[i][j], 0, 0, 0);
        }
        __syncthreads();
    }

#pragma unroll
    for (int i = 0; i < 4; i++) {
#pragma unroll
        for (int rr = 0; rr < 4; rr++) {
            int m = m0 + wr + (i << 4) + (l4 << 2) + rr;
            if (m < cnt) {
                size_t go = (size_t)(rb + m) * N + n0 + wc + l15;
#pragma unroll
                for (int j = 0; j < 4; j++) {
                    float v = acc[i][j][rr];
                    size_t idx = go + (size_t)(j << 4);
                    if (EPI == 2) {
                        ((float*)Out)[idx] = v;
                    } else if (EPI == 1) {
                        float g = (float)Gin[idx];
                        float h = g / (1.f + __expf(-g)) * v;
                        ((_Float16*)Out)[idx] = (_Float16)h;
                    } else {
                        ((_Float16*)Out)[idx] = (_Float16)v;
                    }
                }
            }
        }
    }
}

// ---------------- combine ----------------
__global__ __launch_bounds__(256) void k_combine(
    const float* __restrict__ Y,
    const int* __restrict__ pair_exp, const int* __restrict__ pair_pos,
    const float* __restrict__ topp, const int* __restrict__ eoff,
    float* __restrict__ out)
{
    int t = blockIdx.x;
    int c4 = threadIdx.x * 4;
    int e0 = pair_exp[t * 2], e1 = pair_exp[t * 2 + 1];
    size_t r0 = (size_t)(eoff[e0] + pair_pos[t * 2]);
    size_t r1 = (size_t)(eoff[e1] + pair_pos[t * 2 + 1]);
    float p0 = topp[t * 2], p1 = topp[t * 2 + 1];
    float4 a = *(const float4*)&Y[r0 * DM + c4];
    float4 b = *(const float4*)&Y[r1 * DM + c4];
    float4 o;
    o.x = p0 * a.x + p1 * b.x;
    o.y = p0 * a.y + p1 * b.y;
    o.z = p0 * a.z + p1 * b.z;
    o.w = p0 * a.w + p1 * b.w;
    *(float4*)&out[(size_t)t * DM + c4] = o;
}

extern "C" void kernel_launch(void* const* d_in, const int* in_sizes, int n_in,
                              void* d_out, int out_size, void* d_ws, size_t ws_size,
                              hipStream_t stream)
{
    const float* x  = (const float*)d_in[0];
    const float* rw = (const float*)d_in[1];
    const float* w1 = (const float*)d_in[2];
    const float* w3 = (const float*)d_in[3];
    const float* w2 = (const float*)d_in[4];
    float* out = (float*)d_out;

    char* ws = (char*)d_ws;
    int*   counts    = (int*)ws;
    float* probs_sum = (float*)(ws + 64);
    int*   eoff      = (int*)(ws + 128);
    int*   pair_exp  = (int*)(ws + 256);
    int*   pair_pos  = (int*)(ws + 256 + NROWS * 4);
    float* topp      = (float*)(ws + 256 + 2 * NROWS * 4);

    _Float16* Xg = (_Float16*)(ws + ((size_t)1 << 20));    // 8 MiB: [4096][1024]
    _Float16* G  = (_Float16*)(ws + ((size_t)9 << 20));    // 32 MiB: [4096][4096]
    float*    Y  = (float*)   (ws + ((size_t)9 << 20));    // 16 MiB, aliases dead G
    _Float16* H  = (_Float16*)(ws + ((size_t)41 << 20));   // 32 MiB: [4096][4096]
    _Float16* WA = (_Float16*)(ws + ((size_t)73 << 20));   // 64 MiB: w1t then w2t
    _Float16* W3 = (_Float16*)(ws + ((size_t)137 << 20));  // 64 MiB: w3t
    // total ws use: 201 MiB

    k_init<<<1, 64, 0, stream>>>(counts, probs_sum);
    k_router<<<NTOK, 64, 0, stream>>>(x, rw, counts, probs_sum,
                                      pair_exp, pair_pos, topp);
    k_offsets<<<1, 1, 0, stream>>>(counts, probs_sum, eoff, out + (size_t)NTOK * DM);
    k_gather<<<NROWS, 256, 0, stream>>>(x, pair_exp, pair_pos, eoff, Xg);

    k_transpose<<<dim3(DF / 64, DM / 64, NE), 256, 0, stream>>>(w1, WA, DM, DF);
    k_transpose<<<dim3(DF / 64, DM / 64, NE), 256, 0, stream>>>(w3, W3, DM, DF);

    // G = Xg @ w1
    k_gemm<0><<<dim3(DF / 128, 16, NE), 256, 0, stream>>>(Xg, WA, nullptr, G,
                                                          counts, eoff, DM, DF);
    // w2t reuses WA (after gemm<0> consumed w1t)
    k_transpose<<<dim3(DM / 64, DF / 64, NE), 256, 0, stream>>>(w2, WA, DF, DM);
    // H = silu(G) * (Xg @ w3)
    k_gemm<1><<<dim3(DF / 128, 16, NE), 256, 0, stream>>>(Xg, W3, G, H,
                                                          counts, eoff, DM, DF);
    // Y = H @ w2
    k_gemm<2><<<dim3(DM / 128, 16, NE), 256, 0, stream>>>(H, WA, nullptr, Y,
                                                          counts, eoff, DF, DM);

    k_combine<<<NTOK, 256, 0, stream>>>(Y, pair_exp, pair_pos, topp, eoff, out);
}

// Round 3
// 404.614 us; speedup vs baseline: 4.4647x; 1.5100x over previous
//
#include <hip/hip_runtime.h>
#include <hip/hip_bf16.h>
#include <hip/hip_fp16.h>

#define NTOK 2048
#define DM   1024
#define DF   4096
#define NE   8
#define NROWS (NTOK * 2)

typedef _Float16 f16x8 __attribute__((ext_vector_type(8)));
typedef float    f32x4 __attribute__((ext_vector_type(4)));

__device__ __forceinline__ void gload_lds16(const void* g, void* l) {
    __builtin_amdgcn_global_load_lds(
        (const __attribute__((address_space(1))) void*)g,
        (__attribute__((address_space(3))) void*)l, 16, 0, 0);
}

// ---------------- init ----------------
__global__ void k_init(int* counts, float* probs_sum) {
    int i = threadIdx.x;
    if (i < NE) { counts[i] = 0; probs_sum[i] = 0.f; }
}

// ---------------- router: 32 blocks x 1024 threads, 16 lanes per token ----------------
__global__ __launch_bounds__(1024) void k_router(
    const float* __restrict__ x, const float* __restrict__ rw,
    int* counts, float* probs_sum,
    int* pair_exp, int* pair_pos, float* topp)
{
    __shared__ float lprobs[NE];
    __shared__ int   lcount[NE];
    __shared__ int   lbase[NE];

    int tid = threadIdx.x;
    if (tid < NE) { lprobs[tid] = 0.f; lcount[tid] = 0; }
    __syncthreads();

    int lane = tid & 63;
    int wave = tid >> 6;                 // 0..15
    int sub  = lane >> 4;                // 0..3
    int l16  = lane & 15;
    int t = blockIdx.x * 64 + wave * 4 + sub;

    const float* xt = x + (size_t)t * DM;
    float acc[NE];
#pragma unroll
    for (int e = 0; e < NE; e++) acc[e] = 0.f;

#pragma unroll
    for (int i0 = 0; i0 < DM; i0 += 64) {
        int i = i0 + l16 * 4;
        float4 xv = *(const float4*)(xt + i);
#pragma unroll
        for (int e = 0; e < NE; e++) {
            float4 wv = *(const float4*)(rw + e * DM + i);
            acc[e] = fmaf(xv.x, wv.x, acc[e]);
            acc[e] = fmaf(xv.y, wv.y, acc[e]);
            acc[e] = fmaf(xv.z, wv.z, acc[e]);
            acc[e] = fmaf(xv.w, wv.w, acc[e]);
        }
    }
#pragma unroll
    for (int m = 1; m < 16; m <<= 1)
#pragma unroll
        for (int e = 0; e < NE; e++)
            acc[e] += __shfl_xor(acc[e], m);

    int i0e = 0, i1e = 0, r0 = 0, r1 = 0;
    if (l16 == 0) {
        float mx = acc[0];
#pragma unroll
        for (int e = 1; e < NE; e++) mx = fmaxf(mx, acc[e]);
        float p[NE]; float s = 0.f;
#pragma unroll
        for (int e = 0; e < NE; e++) { p[e] = expf(acc[e] - mx); s += p[e]; }
        float inv = 1.f / s;
#pragma unroll
        for (int e = 0; e < NE; e++) atomicAdd(&lprobs[e], p[e] * inv);

        i0e = 0;
#pragma unroll
        for (int e = 1; e < NE; e++) if (acc[e] > acc[i0e]) i0e = e;
        i1e = (i0e == 0) ? 1 : 0;
#pragma unroll
        for (int e = 0; e < NE; e++) if (e != i0e && acc[e] > acc[i1e]) i1e = e;

        float e1 = expf(acc[i1e] - acc[i0e]);
        float den = 1.f / (1.f + e1);
        topp[t * 2 + 0] = den;
        topp[t * 2 + 1] = e1 * den;
        pair_exp[t * 2 + 0] = i0e;
        pair_exp[t * 2 + 1] = i1e;
        r0 = atomicAdd(&lcount[i0e], 1);
        r1 = atomicAdd(&lcount[i1e], 1);
    }
    __syncthreads();
    if (tid < NE) {
        lbase[tid] = atomicAdd(&counts[tid], lcount[tid]);
        atomicAdd(&probs_sum[tid], lprobs[tid]);
    }
    __syncthreads();
    if (l16 == 0) {
        pair_pos[t * 2 + 0] = lbase[i0e] + r0;
        pair_pos[t * 2 + 1] = lbase[i1e] + r1;
    }
}

// ---------------- offsets + aux loss ----------------
__global__ void k_offsets(const int* counts, const float* probs_sum,
                          int* eoff, float* out_aux)
{
    if (threadIdx.x == 0 && blockIdx.x == 0) {
        int off = 0;
        for (int e = 0; e < NE; e++) { eoff[e] = off; off += counts[e]; }
        eoff[NE] = off;
        float aux = 0.f;
        for (int e = 0; e < NE; e++) {
            float ep = probs_sum[e] / (float)NTOK;
            aux += ep * ep;
        }
        out_aux[0] = 0.01f * (float)NE * aux;
    }
}

// ---------------- gather tokens into grouped rows (fp32 -> fp16) ----------------
__global__ __launch_bounds__(256) void k_gather(
    const float* __restrict__ x, const int* __restrict__ pair_exp,
    const int* __restrict__ pair_pos, const int* __restrict__ eoff,
    _Float16* __restrict__ Xg)
{
    int b = blockIdx.x;
    int t = b >> 1, s = b & 1;
    int e = pair_exp[t * 2 + s];
    int row = eoff[e] + pair_pos[t * 2 + s];
    int c = threadIdx.x << 2;
    float4 v = *(const float4*)(x + (size_t)t * DM + c);
    _Float16 h0 = (_Float16)v.x, h1 = (_Float16)v.y,
             h2 = (_Float16)v.z, h3 = (_Float16)v.w;
    ushort4 o = make_ushort4(*(unsigned short*)&h0, *(unsigned short*)&h1,
                             *(unsigned short*)&h2, *(unsigned short*)&h3);
    *(ushort4*)(Xg + (size_t)row * DM + c) = o;
}

// ---------------- transpose + convert: W[e][K][N] fp32 -> Wt[e][N][K] fp16 ----------------
__global__ __launch_bounds__(256) void k_transpose(
    const float* __restrict__ W, _Float16* __restrict__ Wt, int K, int N)
{
    int e = blockIdx.z;
    int n0 = blockIdx.x << 6, k0 = blockIdx.y << 6;
    const float* src = W + (size_t)e * K * N;
    _Float16* dst = Wt + (size_t)e * N * K;
    __shared__ float tile[64][65];
    int tid = threadIdx.x;
    int tk = tid >> 4, tn = (tid & 15) << 2;
#pragma unroll
    for (int r = 0; r < 4; r++) {
        float4 v = *(const float4*)(src + (size_t)(k0 + tk + (r << 4)) * N + n0 + tn);
        float* trow = &tile[tk + (r << 4)][tn];
        trow[0] = v.x; trow[1] = v.y; trow[2] = v.z; trow[3] = v.w;
    }
    __syncthreads();
    int on = tid >> 2, ok = (tid & 3) << 4;
    unsigned pk[8];
#pragma unroll
    for (int p2 = 0; p2 < 8; p2++) {
        _Float16 a = (_Float16)tile[ok + 2 * p2][on];
        _Float16 b = (_Float16)tile[ok + 2 * p2 + 1][on];
        pk[p2] = (unsigned)(*(unsigned short*)&a) | ((unsigned)(*(unsigned short*)&b) << 16);
    }
    _Float16* d = dst + (size_t)(n0 + on) * K + k0 + ok;
    *(uint4*)d       = make_uint4(pk[0], pk[1], pk[2], pk[3]);
    *(uint4*)(d + 8) = make_uint4(pk[4], pk[5], pk[6], pk[7]);
}

// ---------------- grouped GEMM: C[m][n] = sum_k A[m][k] * Bt[n][k] ----------------
// EPI: 0 = store fp16 (gate G), 1 = read G, store fp16 silu(G)*acc (H), 2 = store fp32 (Y)
template<int EPI>
__global__ __launch_bounds__(256, 3) void k_gemm(
    const _Float16* __restrict__ A, const _Float16* __restrict__ Bt,
    const _Float16* __restrict__ Gin, void* __restrict__ Out,
    const int* __restrict__ counts, const int* __restrict__ eoff,
    int K, int N)
{
    int e = blockIdx.z;
    int cnt = counts[e];
    int m0 = blockIdx.y << 7;
    if (m0 >= cnt) return;
    int n0 = blockIdx.x << 7;
    int rb = eoff[e];

    __shared__ __align__(16) unsigned char sA[16384];   // [128][64] f16, slot-swizzled
    __shared__ __align__(16) unsigned char sB[16384];

    int tid = threadIdx.x;
    int lane = tid & 63;
    int w = tid >> 6;
    int wr = (w >> 1) << 6, wc = (w & 1) << 6;
    int l15 = lane & 15, l4 = lane >> 4;

    const _Float16* Ab = A + (size_t)(rb + m0) * K;
    const _Float16* Bb = Bt + ((size_t)e * N + n0) * K;

    f32x4 acc[4][4];
#pragma unroll
    for (int i = 0; i < 4; i++)
#pragma unroll
        for (int j = 0; j < 4; j++) acc[i][j] = (f32x4){0.f, 0.f, 0.f, 0.f};

    for (int k0 = 0; k0 < K; k0 += 64) {
        // stage: linear LDS dest, inverse-swizzled global source (16B chunks)
#pragma unroll
        for (int i = 0; i < 4; i++) {
            int c = (i << 8) + tid;
            int row = c >> 3;
            int sl = (c & 7) ^ (row & 7);
            size_t go = (size_t)row * K + k0 + (sl << 3);
            gload_lds16(Ab + go, sA + (c << 4));
            gload_lds16(Bb + go, sB + (c << 4));
        }
        __syncthreads();
#pragma unroll
        for (int kk = 0; kk < 2; kk++) {
            f16x8 af[4], bfr[4];
#pragma unroll
            for (int i = 0; i < 4; i++) {
                int r = wr + (i << 4) + l15;
                af[i] = *(const f16x8*)(sA + (r << 7) + ((((kk << 2) + l4) ^ (r & 7)) << 4));
            }
#pragma unroll
            for (int j = 0; j < 4; j++) {
                int r = wc + (j << 4) + l15;
                bfr[j] = *(const f16x8*)(sB + (r << 7) + ((((kk << 2) + l4) ^ (r & 7)) << 4));
            }
#pragma unroll
            for (int i = 0; i < 4; i++)
#pragma unroll
                for (int j = 0; j < 4; j++)
                    acc[i][j] = __builtin_amdgcn_mfma_f32_16x16x32_f16(af[i], bfr[j], acc[i][j], 0, 0, 0);
        }
        __syncthreads();
    }

#pragma unroll
    for (int i = 0; i < 4; i++) {
#pragma unroll
        for (int rr = 0; rr < 4; rr++) {
            int m = m0 + wr + (i << 4) + (l4 << 2) + rr;
            if (m < cnt) {
                size_t go = (size_t)(rb + m) * N + n0 + wc + l15;
#pragma unroll
                for (int j = 0; j < 4; j++) {
                    float v = acc[i][j][rr];
                    size_t idx = go + (size_t)(j << 4);
                    if (EPI == 2) {
                        ((float*)Out)[idx] = v;
                    } else if (EPI == 1) {
                        float g = (float)Gin[idx];
                        float h = g / (1.f + __expf(-g)) * v;
                        ((_Float16*)Out)[idx] = (_Float16)h;
                    } else {
                        ((_Float16*)Out)[idx] = (_Float16)v;
                    }
                }
            }
        }
    }
}

// ---------------- combine ----------------
__global__ __launch_bounds__(256) void k_combine(
    const float* __restrict__ Y,
    const int* __restrict__ pair_exp, const int* __restrict__ pair_pos,
    const float* __restrict__ topp, const int* __restrict__ eoff,
    float* __restrict__ out)
{
    int t = blockIdx.x;
    int c4 = threadIdx.x * 4;
    int e0 = pair_exp[t * 2], e1 = pair_exp[t * 2 + 1];
    size_t r0 = (size_t)(eoff[e0] + pair_pos[t * 2]);
    size_t r1 = (size_t)(eoff[e1] + pair_pos[t * 2 + 1]);
    float p0 = topp[t * 2], p1 = topp[t * 2 + 1];
    float4 a = *(const float4*)&Y[r0 * DM + c4];
    float4 b = *(const float4*)&Y[r1 * DM + c4];
    float4 o;
    o.x = p0 * a.x + p1 * b.x;
    o.y = p0 * a.y + p1 * b.y;
    o.z = p0 * a.z + p1 * b.z;
    o.w = p0 * a.w + p1 * b.w;
    *(float4*)&out[(size_t)t * DM + c4] = o;
}

extern "C" void kernel_launch(void* const* d_in, const int* in_sizes, int n_in,
                              void* d_out, int out_size, void* d_ws, size_t ws_size,
                              hipStream_t stream)
{
    const float* x  = (const float*)d_in[0];
    const float* rw = (const float*)d_in[1];
    const float* w1 = (const float*)d_in[2];
    const float* w3 = (const float*)d_in[3];
    const float* w2 = (const float*)d_in[4];
    float* out = (float*)d_out;

    char* ws = (char*)d_ws;
    int*   counts    = (int*)ws;
    float* probs_sum = (float*)(ws + 64);
    int*   eoff      = (int*)(ws + 128);
    int*   pair_exp  = (int*)(ws + 256);
    int*   pair_pos  = (int*)(ws + 256 + NROWS * 4);
    float* topp      = (float*)(ws + 256 + 2 * NROWS * 4);

    _Float16* Xg = (_Float16*)(ws + ((size_t)1 << 20));    // 8 MiB: [4096][1024]
    _Float16* G  = (_Float16*)(ws + ((size_t)9 << 20));    // 32 MiB: [4096][4096]
    float*    Y  = (float*)   (ws + ((size_t)9 << 20));    // 16 MiB, aliases dead G
    _Float16* H  = (_Float16*)(ws + ((size_t)41 << 20));   // 32 MiB: [4096][4096]
    _Float16* WA = (_Float16*)(ws + ((size_t)73 << 20));   // 64 MiB: w1t then w2t
    _Float16* W3 = (_Float16*)(ws + ((size_t)137 << 20));  // 64 MiB: w3t
    // total ws use: 201 MiB

    k_init<<<1, 64, 0, stream>>>(counts, probs_sum);
    k_router<<<NTOK / 64, 1024, 0, stream>>>(x, rw, counts, probs_sum,
                                             pair_exp, pair_pos, topp);
    k_offsets<<<1, 1, 0, stream>>>(counts, probs_sum, eoff, out + (size_t)NTOK * DM);
    k_gather<<<NROWS, 256, 0, stream>>>(x, pair_exp, pair_pos, eoff, Xg);

    k_transpose<<<dim3(DF / 64, DM / 64, NE), 256, 0, stream>>>(w1, WA, DM, DF);
    k_transpose<<<dim3(DF / 64, DM / 64, NE), 256, 0, stream>>>(w3, W3, DM, DF);

    // G = Xg @ w1
    k_gemm<0><<<dim3(DF / 128, 16, NE), 256, 0, stream>>>(Xg, WA, nullptr, G,
                                                          counts, eoff, DM, DF);
    // w2t reuses WA (after gemm<0> consumed w1t)
    k_transpose<<<dim3(DM / 64, DF / 64, NE), 256, 0, stream>>>(w2, WA, DF, DM);
    // H = silu(G) * (Xg @ w3)
    k_gemm<1><<<dim3(DF / 128, 16, NE), 256, 0, stream>>>(Xg, W3, G, H,
                                                          counts, eoff, DM, DF);
    // Y = H @ w2
    k_gemm<2><<<dim3(DM / 128, 16, NE), 256, 0, stream>>>(H, WA, nullptr, Y,
                                                          counts, eoff, DF, DM);

    k_combine<<<NTOK, 256, 0, stream>>>(Y, pair_exp, pair_pos, topp, eoff, out);
}

// Round 4
// 346.669 us; speedup vs baseline: 5.2109x; 1.1671x over previous
//
#include <hip/hip_runtime.h>
#include <hip/hip_bf16.h>
#include <hip/hip_fp16.h>

#define NTOK 2048
#define DM   1024
#define DF   4096
#define NE   8
#define NROWS (NTOK * 2)
#define NSPLIT 4
#define KSPL (DF / NSPLIT)

typedef _Float16 f16x8 __attribute__((ext_vector_type(8)));
typedef float    f32x4 __attribute__((ext_vector_type(4)));

__device__ __forceinline__ void gload_lds16(const void* g, void* l) {
    __builtin_amdgcn_global_load_lds(
        (const __attribute__((address_space(1))) void*)g,
        (__attribute__((address_space(3))) void*)l, 16, 0, 0);
}

// ---------------- init ----------------
__global__ void k_init(int* counts, float* probs_sum) {
    int i = threadIdx.x;
    if (i < NE) { counts[i] = 0; probs_sum[i] = 0.f; }
}

// ---------------- router: 32 blocks x 1024 threads, 16 lanes per token ----------------
__global__ __launch_bounds__(1024) void k_router(
    const float* __restrict__ x, const float* __restrict__ rw,
    int* counts, float* probs_sum,
    int* pair_exp, int* pair_pos, float* topp)
{
    __shared__ float lprobs[NE];
    __shared__ int   lcount[NE];
    __shared__ int   lbase[NE];

    int tid = threadIdx.x;
    if (tid < NE) { lprobs[tid] = 0.f; lcount[tid] = 0; }
    __syncthreads();

    int lane = tid & 63;
    int wave = tid >> 6;
    int sub  = lane >> 4;
    int l16  = lane & 15;
    int t = blockIdx.x * 64 + wave * 4 + sub;

    const float* xt = x + (size_t)t * DM;
    float acc[NE];
#pragma unroll
    for (int e = 0; e < NE; e++) acc[e] = 0.f;

#pragma unroll
    for (int i0 = 0; i0 < DM; i0 += 64) {
        int i = i0 + l16 * 4;
        float4 xv = *(const float4*)(xt + i);
#pragma unroll
        for (int e = 0; e < NE; e++) {
            float4 wv = *(const float4*)(rw + e * DM + i);
            acc[e] = fmaf(xv.x, wv.x, acc[e]);
            acc[e] = fmaf(xv.y, wv.y, acc[e]);
            acc[e] = fmaf(xv.z, wv.z, acc[e]);
            acc[e] = fmaf(xv.w, wv.w, acc[e]);
        }
    }
#pragma unroll
    for (int m = 1; m < 16; m <<= 1)
#pragma unroll
        for (int e = 0; e < NE; e++)
            acc[e] += __shfl_xor(acc[e], m);

    int i0e = 0, i1e = 0, r0 = 0, r1 = 0;
    if (l16 == 0) {
        float mx = acc[0];
#pragma unroll
        for (int e = 1; e < NE; e++) mx = fmaxf(mx, acc[e]);
        float p[NE]; float s = 0.f;
#pragma unroll
        for (int e = 0; e < NE; e++) { p[e] = expf(acc[e] - mx); s += p[e]; }
        float inv = 1.f / s;
#pragma unroll
        for (int e = 0; e < NE; e++) atomicAdd(&lprobs[e], p[e] * inv);

        i0e = 0;
#pragma unroll
        for (int e = 1; e < NE; e++) if (acc[e] > acc[i0e]) i0e = e;
        i1e = (i0e == 0) ? 1 : 0;
#pragma unroll
        for (int e = 0; e < NE; e++) if (e != i0e && acc[e] > acc[i1e]) i1e = e;

        float e1 = expf(acc[i1e] - acc[i0e]);
        float den = 1.f / (1.f + e1);
        topp[t * 2 + 0] = den;
        topp[t * 2 + 1] = e1 * den;
        pair_exp[t * 2 + 0] = i0e;
        pair_exp[t * 2 + 1] = i1e;
        r0 = atomicAdd(&lcount[i0e], 1);
        r1 = atomicAdd(&lcount[i1e], 1);
    }
    __syncthreads();
    if (tid < NE) {
        lbase[tid] = atomicAdd(&counts[tid], lcount[tid]);
        atomicAdd(&probs_sum[tid], lprobs[tid]);
    }
    __syncthreads();
    if (l16 == 0) {
        pair_pos[t * 2 + 0] = lbase[i0e] + r0;
        pair_pos[t * 2 + 1] = lbase[i1e] + r1;
    }
}

// ---------------- offsets + aux loss ----------------
__global__ void k_offsets(const int* counts, const float* probs_sum,
                          int* eoff, float* out_aux)
{
    if (threadIdx.x == 0 && blockIdx.x == 0) {
        int off = 0;
        for (int e = 0; e < NE; e++) { eoff[e] = off; off += counts[e]; }
        eoff[NE] = off;
        float aux = 0.f;
        for (int e = 0; e < NE; e++) {
            float ep = probs_sum[e] / (float)NTOK;
            aux += ep * ep;
        }
        out_aux[0] = 0.01f * (float)NE * aux;
    }
}

// ---------------- gather tokens into grouped rows (fp32 -> fp16) ----------------
__global__ __launch_bounds__(256) void k_gather(
    const float* __restrict__ x, const int* __restrict__ pair_exp,
    const int* __restrict__ pair_pos, const int* __restrict__ eoff,
    _Float16* __restrict__ Xg)
{
    int b = blockIdx.x;
    int t = b >> 1, s = b & 1;
    int e = pair_exp[t * 2 + s];
    int row = eoff[e] + pair_pos[t * 2 + s];
    int c = threadIdx.x << 2;
    float4 v = *(const float4*)(x + (size_t)t * DM + c);
    _Float16 h0 = (_Float16)v.x, h1 = (_Float16)v.y,
             h2 = (_Float16)v.z, h3 = (_Float16)v.w;
    ushort4 o = make_ushort4(*(unsigned short*)&h0, *(unsigned short*)&h1,
                             *(unsigned short*)&h2, *(unsigned short*)&h3);
    *(ushort4*)(Xg + (size_t)row * DM + c) = o;
}

// ---------------- transpose + convert: W[e][K][N] fp32 -> Wt[e][N][K] fp16 ----------------
__global__ __launch_bounds__(256) void k_transpose(
    const float* __restrict__ W, _Float16* __restrict__ Wt, int K, int N)
{
    int e = blockIdx.z;
    int n0 = blockIdx.x << 6, k0 = blockIdx.y << 6;
    const float* src = W + (size_t)e * K * N;
    _Float16* dst = Wt + (size_t)e * N * K;
    __shared__ float tile[64][65];
    int tid = threadIdx.x;
    int tk = tid >> 4, tn = (tid & 15) << 2;
#pragma unroll
    for (int r = 0; r < 4; r++) {
        float4 v = *(const float4*)(src + (size_t)(k0 + tk + (r << 4)) * N + n0 + tn);
        float* trow = &tile[tk + (r << 4)][tn];
        trow[0] = v.x; trow[1] = v.y; trow[2] = v.z; trow[3] = v.w;
    }
    __syncthreads();
    int on = tid >> 2, ok = (tid & 3) << 4;
    unsigned pk[8];
#pragma unroll
    for (int p2 = 0; p2 < 8; p2++) {
        _Float16 a = (_Float16)tile[ok + 2 * p2][on];
        _Float16 b = (_Float16)tile[ok + 2 * p2 + 1][on];
        pk[p2] = (unsigned)(*(unsigned short*)&a) | ((unsigned)(*(unsigned short*)&b) << 16);
    }
    _Float16* d = dst + (size_t)(n0 + on) * K + k0 + ok;
    *(uint4*)d       = make_uint4(pk[0], pk[1], pk[2], pk[3]);
    *(uint4*)(d + 8) = make_uint4(pk[4], pk[5], pk[6], pk[7]);
}

// ---------------- fused FFN1: H = silu(Xg W1) * (Xg W3), dual-B grouped GEMM ----------------
__global__ __launch_bounds__(256, 2) void k_ffn1(
    const _Float16* __restrict__ A, const _Float16* __restrict__ B1t,
    const _Float16* __restrict__ B3t, _Float16* __restrict__ H,
    const int* __restrict__ counts, const int* __restrict__ eoff)
{
    int e = blockIdx.z;
    int cnt = counts[e];
    int m0 = blockIdx.y << 7;
    if (m0 >= cnt) return;
    int n0 = blockIdx.x << 7;
    int rb = eoff[e];

    __shared__ __align__(16) unsigned char sA[16384];    // [128][64] f16, slot-swizzled
    __shared__ __align__(16) unsigned char sB1[16384];
    __shared__ __align__(16) unsigned char sB3[16384];

    int tid = threadIdx.x;
    int lane = tid & 63;
    int w = tid >> 6;
    int wr = (w >> 1) << 6, wc = (w & 1) << 6;
    int l15 = lane & 15, l4 = lane >> 4;

    const _Float16* Ab  = A   + (size_t)(rb + m0) * DM;
    const _Float16* B1b = B1t + ((size_t)e * DF + n0) * DM;
    const _Float16* B3b = B3t + ((size_t)e * DF + n0) * DM;

    f32x4 accg[4][4], accu[4][4];
#pragma unroll
    for (int i = 0; i < 4; i++)
#pragma unroll
        for (int j = 0; j < 4; j++) {
            accg[i][j] = (f32x4){0.f, 0.f, 0.f, 0.f};
            accu[i][j] = (f32x4){0.f, 0.f, 0.f, 0.f};
        }

    for (int k0 = 0; k0 < DM; k0 += 64) {
#pragma unroll
        for (int i = 0; i < 4; i++) {
            int c = (i << 8) + tid;
            int row = c >> 3;
            int sl = (c & 7) ^ (row & 7);
            size_t go = (size_t)row * DM + k0 + (sl << 3);
            gload_lds16(Ab  + go, sA  + (c << 4));
            gload_lds16(B1b + go, sB1 + (c << 4));
            gload_lds16(B3b + go, sB3 + (c << 4));
        }
        __syncthreads();
#pragma unroll
        for (int kk = 0; kk < 2; kk++) {
            f16x8 af[4], b1f[4], b3f[4];
#pragma unroll
            for (int i = 0; i < 4; i++) {
                int r = wr + (i << 4) + l15;
                af[i] = *(const f16x8*)(sA + (r << 7) + ((((kk << 2) + l4) ^ (r & 7)) << 4));
            }
#pragma unroll
            for (int j = 0; j < 4; j++) {
                int r = wc + (j << 4) + l15;
                int off = (r << 7) + ((((kk << 2) + l4) ^ (r & 7)) << 4);
                b1f[j] = *(const f16x8*)(sB1 + off);
                b3f[j] = *(const f16x8*)(sB3 + off);
            }
#pragma unroll
            for (int i = 0; i < 4; i++)
#pragma unroll
                for (int j = 0; j < 4; j++) {
                    accg[i][j] = __builtin_amdgcn_mfma_f32_16x16x32_f16(af[i], b1f[j], accg[i][j], 0, 0, 0);
                    accu[i][j] = __builtin_amdgcn_mfma_f32_16x16x32_f16(af[i], b3f[j], accu[i][j], 0, 0, 0);
                }
        }
        __syncthreads();
    }

#pragma unroll
    for (int i = 0; i < 4; i++) {
#pragma unroll
        for (int rr = 0; rr < 4; rr++) {
            int m = m0 + wr + (i << 4) + (l4 << 2) + rr;
            if (m < cnt) {
                size_t go = (size_t)(rb + m) * DF + n0 + wc + l15;
#pragma unroll
                for (int j = 0; j < 4; j++) {
                    float g = accg[i][j][rr];
                    float u = accu[i][j][rr];
                    float h = g / (1.f + __expf(-g)) * u;
                    H[go + (size_t)(j << 4)] = (_Float16)h;
                }
            }
        }
    }
}

// ---------------- split-K grouped GEMM: Yp[sp] = H W2 (partial over K chunk) ----------------
__global__ __launch_bounds__(256, 3) void k_gemm2(
    const _Float16* __restrict__ A, const _Float16* __restrict__ Bt,
    float* __restrict__ Yp,
    const int* __restrict__ counts, const int* __restrict__ eoff)
{
    int z = blockIdx.z;
    int e = z >> 2, sp = z & 3;
    int cnt = counts[e];
    int m0 = blockIdx.y << 7;
    if (m0 >= cnt) return;
    int n0 = blockIdx.x << 7;
    int rb = eoff[e];

    __shared__ __align__(16) unsigned char sA[16384];
    __shared__ __align__(16) unsigned char sB[16384];

    int tid = threadIdx.x;
    int lane = tid & 63;
    int w = tid >> 6;
    int wr = (w >> 1) << 6, wc = (w & 1) << 6;
    int l15 = lane & 15, l4 = lane >> 4;

    const _Float16* Ab = A + (size_t)(rb + m0) * DF;
    const _Float16* Bb = Bt + ((size_t)e * DM + n0) * DF;

    f32x4 acc[4][4];
#pragma unroll
    for (int i = 0; i < 4; i++)
#pragma unroll
        for (int j = 0; j < 4; j++) acc[i][j] = (f32x4){0.f, 0.f, 0.f, 0.f};

    for (int k0 = sp * KSPL; k0 < (sp + 1) * KSPL; k0 += 64) {
#pragma unroll
        for (int i = 0; i < 4; i++) {
            int c = (i << 8) + tid;
            int row = c >> 3;
            int sl = (c & 7) ^ (row & 7);
            size_t go = (size_t)row * DF + k0 + (sl << 3);
            gload_lds16(Ab + go, sA + (c << 4));
            gload_lds16(Bb + go, sB + (c << 4));
        }
        __syncthreads();
#pragma unroll
        for (int kk = 0; kk < 2; kk++) {
            f16x8 af[4], bfr[4];
#pragma unroll
            for (int i = 0; i < 4; i++) {
                int r = wr + (i << 4) + l15;
                af[i] = *(const f16x8*)(sA + (r << 7) + ((((kk << 2) + l4) ^ (r & 7)) << 4));
            }
#pragma unroll
            for (int j = 0; j < 4; j++) {
                int r = wc + (j << 4) + l15;
                bfr[j] = *(const f16x8*)(sB + (r << 7) + ((((kk << 2) + l4) ^ (r & 7)) << 4));
            }
#pragma unroll
            for (int i = 0; i < 4; i++)
#pragma unroll
                for (int j = 0; j < 4; j++)
                    acc[i][j] = __builtin_amdgcn_mfma_f32_16x16x32_f16(af[i], bfr[j], acc[i][j], 0, 0, 0);
        }
        __syncthreads();
    }

    float* Yo = Yp + (size_t)sp * NROWS * DM;
#pragma unroll
    for (int i = 0; i < 4; i++) {
#pragma unroll
        for (int rr = 0; rr < 4; rr++) {
            int m = m0 + wr + (i << 4) + (l4 << 2) + rr;
            if (m < cnt) {
                size_t go = (size_t)(rb + m) * DM + n0 + wc + l15;
#pragma unroll
                for (int j = 0; j < 4; j++)
                    Yo[go + (size_t)(j << 4)] = acc[i][j][rr];
            }
        }
    }
}

// ---------------- combine: out[t] = p0*sum_sp Yp[sp][r0] + p1*sum_sp Yp[sp][r1] ----------------
__global__ __launch_bounds__(256) void k_combine(
    const float* __restrict__ Yp,
    const int* __restrict__ pair_exp, const int* __restrict__ pair_pos,
    const float* __restrict__ topp, const int* __restrict__ eoff,
    float* __restrict__ out)
{
    int t = blockIdx.x;
    int c4 = threadIdx.x * 4;
    int e0 = pair_exp[t * 2], e1 = pair_exp[t * 2 + 1];
    size_t r0 = (size_t)(eoff[e0] + pair_pos[t * 2]);
    size_t r1 = (size_t)(eoff[e1] + pair_pos[t * 2 + 1]);
    float p0 = topp[t * 2], p1 = topp[t * 2 + 1];

    float4 a = make_float4(0.f, 0.f, 0.f, 0.f);
    float4 b = make_float4(0.f, 0.f, 0.f, 0.f);
#pragma unroll
    for (int sp = 0; sp < NSPLIT; sp++) {
        const float* base = Yp + (size_t)sp * NROWS * DM;
        float4 va = *(const float4*)&base[r0 * DM + c4];
        float4 vb = *(const float4*)&base[r1 * DM + c4];
        a.x += va.x; a.y += va.y; a.z += va.z; a.w += va.w;
        b.x += vb.x; b.y += vb.y; b.z += vb.z; b.w += vb.w;
    }
    float4 o;
    o.x = p0 * a.x + p1 * b.x;
    o.y = p0 * a.y + p1 * b.y;
    o.z = p0 * a.z + p1 * b.z;
    o.w = p0 * a.w + p1 * b.w;
    *(float4*)&out[(size_t)t * DM + c4] = o;
}

extern "C" void kernel_launch(void* const* d_in, const int* in_sizes, int n_in,
                              void* d_out, int out_size, void* d_ws, size_t ws_size,
                              hipStream_t stream)
{
    const float* x  = (const float*)d_in[0];
    const float* rw = (const float*)d_in[1];
    const float* w1 = (const float*)d_in[2];
    const float* w3 = (const float*)d_in[3];
    const float* w2 = (const float*)d_in[4];
    float* out = (float*)d_out;

    char* ws = (char*)d_ws;
    int*   counts    = (int*)ws;
    float* probs_sum = (float*)(ws + 64);
    int*   eoff      = (int*)(ws + 128);
    int*   pair_exp  = (int*)(ws + 256);
    int*   pair_pos  = (int*)(ws + 256 + NROWS * 4);
    float* topp      = (float*)(ws + 256 + 2 * NROWS * 4);

    _Float16* Xg = (_Float16*)(ws + ((size_t)1 << 20));    // 8 MiB: [4096][1024] f16
    _Float16* H  = (_Float16*)(ws + ((size_t)9 << 20));    // 32 MiB: [4096][4096] f16
    _Float16* WA = (_Float16*)(ws + ((size_t)41 << 20));   // 64 MiB: w1t, then w2t
    _Float16* WB = (_Float16*)(ws + ((size_t)105 << 20));  // 64 MiB: w3t, then Yp
    float*    Yp = (float*)WB;                             // 4 x [4096][1024] f32 = 64 MiB
    // total ws use: 169 MiB

    k_init<<<1, 64, 0, stream>>>(counts, probs_sum);
    k_router<<<NTOK / 64, 1024, 0, stream>>>(x, rw, counts, probs_sum,
                                             pair_exp, pair_pos, topp);
    k_offsets<<<1, 1, 0, stream>>>(counts, probs_sum, eoff, out + (size_t)NTOK * DM);
    k_gather<<<NROWS, 256, 0, stream>>>(x, pair_exp, pair_pos, eoff, Xg);

    k_transpose<<<dim3(DF / 64, DM / 64, NE), 256, 0, stream>>>(w1, WA, DM, DF);
    k_transpose<<<dim3(DF / 64, DM / 64, NE), 256, 0, stream>>>(w3, WB, DM, DF);

    // H = silu(Xg @ w1) * (Xg @ w3)
    k_ffn1<<<dim3(DF / 128, 16, NE), 256, 0, stream>>>(Xg, WA, WB, H, counts, eoff);

    // w2t reuses WA (w1t dead after ffn1)
    k_transpose<<<dim3(DM / 64, DF / 64, NE), 256, 0, stream>>>(w2, WA, DF, DM);

    // Yp[sp] = H @ w2 partials (Yp aliases WB; w3t dead after ffn1)
    k_gemm2<<<dim3(DM / 128, 16, NE * NSPLIT), 256, 0, stream>>>(H, WA, Yp, counts, eoff);

    k_combine<<<NTOK, 256, 0, stream>>>(Yp, pair_exp, pair_pos, topp, eoff, out);
}